// Round 10
// baseline (149.088 us; speedup 1.0000x reference)
//
#include <hip/hip_runtime.h>
#include <hip/hip_bf16.h>

// B=32, IN_N=8192, POSE=64, M=8, NH=32, S2=256, HID=256, OUT_N=64
//
// Single persistent kernel (256 blocks x 512 thr) + 16B memset for barrier counters.
//  Phase A: pack WCf (bf16 MFMA B-frags of w_current) + fold E_proj -> F.   [grid bar 1]
//  Phase B: S[b,r] = sum_p CP@WC via MFMA 16x16x32 (full p per wave) -> LDS Stile.
//  Phase C: pooled partials: P[b][slot][q] = sum_j Stile[b][j]*F[j,q] (vectorized). [grid bar 2]
//  Phase D: blocks 0..31: pooled = (1/64)*sum P + rel; out = pooled @ w_next.
// Co-residency for spin barriers: launch_bounds(512,4) => <=128 VGPR => >=2 blocks/CU
// capacity = 512 >= 256 grid (2x margin). Barrier counters reset by memset each launch.

typedef short short8_t __attribute__((ext_vector_type(8)));
typedef float f32x4_t __attribute__((ext_vector_type(4)));
typedef int   int4_t  __attribute__((ext_vector_type(4)));

__device__ __forceinline__ int cvt_pk(float x, float y) {
    int r;
    asm("v_cvt_pk_bf16_f32 %0, %1, %2" : "=v"(r) : "v"(x), "v"(y));
    return r;
}

__global__ void __launch_bounds__(512, 4)
k_mega(const float* __restrict__ CP, const float* __restrict__ WC,
       const float* __restrict__ E,  const float* __restrict__ rel,
       const float* __restrict__ WN, float* __restrict__ F,
       short* __restrict__ WCf, float* __restrict__ P,
       unsigned* __restrict__ cnt, float* __restrict__ out)
{
    const int bid = blockIdx.x;      // [0,256): bid = bq*16 + rpg  (same rpg -> same XCD)
    const int rpg = bid & 15;
    const int bq  = bid >> 4;
    const int b0  = bq * 2;
    const int t   = threadIdx.x;     // [0,512)
    const int w   = t >> 6;          // [0,8)
    const int l   = t & 63;

    __shared__ float Stile[2][512];
    __shared__ float red[8][64];
    __shared__ float pool_s[64];

    // ---------- Phase A1: pack WCf[rp in rpg-slice][pc=bq] (threads 0..255) ----------
    if (t < 256) {
        int rp_loc = t >> 6;
        int ll  = t & 63;
        int lhi = ll >> 4;
        int j   = ll & 15;
        int rp  = rpg * 4 + rp_loc;
        int row = (bq * 4 + lhi) * 128 + rp * 2 + (j >> 3);
        const float* src = WC + ((size_t)row << 6) + (j & 7);
        int4_t o;
        o[0] = cvt_pk(src[0],  src[8]);
        o[1] = cvt_pk(src[16], src[24]);
        o[2] = cvt_pk(src[32], src[40]);
        o[3] = cvt_pk(src[48], src[56]);
        ((int4_t*)WCf)[rp * 1024 + bq * 64 + ll] = o;
    }
    // ---------- Phase A2: E-fold slice (all threads, 4 floats each) ----------
    {
        int idx = bid * 2048 + t * 4;     // [0, 524288)
        int q   = idx & 63;
        int row = idx >> 6;
        int r   = row >> 6;
        int e   = row & 63;
        int nh  = r >> 2;
        int s2  = ((r & 3) << 6) + e;
        const float* base = E + (((size_t)nh * 256 + s2) << 8) + q;
        float4 s0 = *(const float4*)(base);
        float4 s1 = *(const float4*)(base + 64);
        float4 s2v = *(const float4*)(base + 128);
        float4 s3 = *(const float4*)(base + 192);
        float4 o;
        o.x = s0.x + s1.x + s2v.x + s3.x;
        o.y = s0.y + s1.y + s2v.y + s3.y;
        o.z = s0.z + s1.z + s2v.z + s3.z;
        o.w = s0.w + s1.w + s2v.w + s3.w;
        *(float4*)(F + idx) = o;
    }

    // ---------- Grid barrier 1 ----------
    __syncthreads();
    __threadfence();
    if (t == 0) {
        __hip_atomic_fetch_add(cnt, 1u, __ATOMIC_ACQ_REL, __HIP_MEMORY_SCOPE_AGENT);
        while (__hip_atomic_load(cnt, __ATOMIC_ACQUIRE, __HIP_MEMORY_SCOPE_AGENT) < 256u)
            __builtin_amdgcn_s_sleep(2);
    }
    __syncthreads();
    __threadfence();

    // ---------- Phase B: stream + MFMA, full p per wave ----------
    {
        int b_loc  = w & 1;
        int rp_loc = w >> 1;
        int rp = rpg * 4 + rp_loc;
        int r0 = rp * 2;
        int b  = b0 + b_loc;
        int i16 = l & 15, r_sel = i16 >> 3, m1 = i16 & 7, lhi = l >> 4;
        const float* cp_base = CP + ((size_t)b << 19) + ((size_t)(r0 + r_sel) << 6) + m1 * 8;
        const short8_t* wf = (const short8_t*)WCf + (size_t)rp * 1024 + l;
        f32x4_t acc = {0.f, 0.f, 0.f, 0.f};
        #pragma unroll
        for (int c = 0; c < 16; ++c) {
            int p = c * 4 + lhi;
            const float* a_ptr = cp_base + ((size_t)p << 13);
            float4 a0 = *(const float4*)(a_ptr);
            float4 a1 = *(const float4*)(a_ptr + 4);
            int4_t ai;
            ai[0] = cvt_pk(a0.x, a0.y);
            ai[1] = cvt_pk(a0.z, a0.w);
            ai[2] = cvt_pk(a1.x, a1.y);
            ai[3] = cvt_pk(a1.z, a1.w);
            acc = __builtin_amdgcn_mfma_f32_16x16x32_bf16(
                __builtin_bit_cast(short8_t, ai), wf[c * 64], acc, 0, 0, 0);
        }
        // C/D layout (m89-verified): col = lane&15, row = (lane>>4)*4 + reg
        int col = i16;
        #pragma unroll
        for (int v = 0; v < 4; ++v) {
            int row = lhi * 4 + v;
            if (row < 8 && col < 8)
                Stile[b_loc][rp_loc * 128 + row * 8 + col] = acc[v];
            else if (row >= 8 && col >= 8)
                Stile[b_loc][rp_loc * 128 + 64 + (row - 8) * 8 + (col - 8)] = acc[v];
        }
    }
    __syncthreads();

    // ---------- Phase C: pool, wave w covers jl in [w*64, w*64+64) for both b's ----------
    {
        int g = l >> 4, ql = l & 15;
        const float* Fb = F + (((size_t)(rpg * 512 + w * 64 + g)) << 6) + ql * 4;
        f32x4_t p0 = {0.f, 0.f, 0.f, 0.f}, p1 = {0.f, 0.f, 0.f, 0.f};
        #pragma unroll 4
        for (int s = 0; s < 16; ++s) {
            int jl = w * 64 + s * 4 + g;
            float4 fv = *(const float4*)(Fb + ((size_t)(s * 4) << 6));
            float s0 = Stile[0][jl], s1 = Stile[1][jl];
            p0[0] += s0 * fv.x; p0[1] += s0 * fv.y; p0[2] += s0 * fv.z; p0[3] += s0 * fv.w;
            p1[0] += s1 * fv.x; p1[1] += s1 * fv.y; p1[2] += s1 * fv.z; p1[3] += s1 * fv.w;
        }
        #pragma unroll
        for (int c4 = 0; c4 < 4; ++c4) {
            p0[c4] += __shfl_xor(p0[c4], 16, 64);
            p0[c4] += __shfl_xor(p0[c4], 32, 64);
            p1[c4] += __shfl_xor(p1[c4], 16, 64);
            p1[c4] += __shfl_xor(p1[c4], 32, 64);
        }
        if (l < 16) {
            int sp = rpg * 8 + w;            // [0,128) slot per b
            float4 o0; o0.x = p0[0]; o0.y = p0[1]; o0.z = p0[2]; o0.w = p0[3];
            float4 o1; o1.x = p1[0]; o1.y = p1[1]; o1.z = p1[2]; o1.w = p1[3];
            *(float4*)(P + ((size_t)((b0 + 0) * 128 + sp) << 6) + ql * 4) = o0;
            *(float4*)(P + ((size_t)((b0 + 1) * 128 + sp) << 6) + ql * 4) = o1;
        }
    }

    // ---------- Grid barrier 2 (arrive all; only bid<32 wait) ----------
    __syncthreads();
    __threadfence();
    if (t == 0)
        __hip_atomic_fetch_add(cnt + 1, 1u, __ATOMIC_ACQ_REL, __HIP_MEMORY_SCOPE_AGENT);
    if (bid >= 32) return;
    if (t == 0) {
        while (__hip_atomic_load(cnt + 1, __ATOMIC_ACQUIRE, __HIP_MEMORY_SCOPE_AGENT) < 256u)
            __builtin_amdgcn_s_sleep(2);
    }
    __syncthreads();
    __threadfence();

    // ---------- Phase D: final for b = bid ----------
    {
        int b_ = bid;
        int q = t & 63, sg = t >> 6;         // 8 groups x 16 slots
        const float* Pb = P + ((size_t)(b_ * 128) << 6);
        float s = 0.f;
        #pragma unroll
        for (int c = sg * 16; c < sg * 16 + 16; ++c)
            s += Pb[((size_t)c << 6) + q];
        red[sg][q] = s;
        __syncthreads();
        if (t < 64) {
            float ss = 0.f;
            #pragma unroll
            for (int gg = 0; gg < 8; ++gg) ss += red[gg][t];
            pool_s[t] = ss * (1.0f / 64.0f) + rel[t];
        }
        __syncthreads();
        #pragma unroll
        for (int idx = t; idx < 4096; idx += 512) {
            int o = idx >> 6, e = idx & 63, mm1 = e >> 3, mm2 = e & 7;
            float a = 0.f;
            #pragma unroll
            for (int k = 0; k < 8; ++k)
                a += pool_s[mm1 * 8 + k] * WN[o * 64 + k * 8 + mm2];
            out[((size_t)b_ << 12) + idx] = a;
        }
    }
}

extern "C" void kernel_launch(void* const* d_in, const int* in_sizes, int n_in,
                              void* d_out, int out_size, void* d_ws, size_t ws_size,
                              hipStream_t stream) {
    const float* current_pose = (const float*)d_in[0];  // (32, 8192, 64)
    const float* w_current    = (const float*)d_in[1];  // (1,1,8192,8,8)
    const float* w_next       = (const float*)d_in[2];  // (64,8,8)
    const float* E_proj       = (const float*)d_in[3];  // (32,256,256)
    const float* rel_embedd   = (const float*)d_in[4];  // (1,1,64)
    float* out = (float*)d_out;                         // (32,1,64,64)

    char* ws = (char*)d_ws;
    float*    F   = (float*)(ws);                 // 2 MiB
    short*    WCf = (short*)(ws + (2u << 20));    // 1 MiB
    float*    P   = (float*)(ws + (3u << 20));    // 1 MiB (32 x 128 x 64)
    unsigned* cnt = (unsigned*)(ws + (4u << 20)); // barrier counters

    hipMemsetAsync(cnt, 0, 16, stream);           // reset barrier counters each launch
    k_mega<<<dim3(256), dim3(512), 0, stream>>>(current_pose, w_current, E_proj,
                                                rel_embedd, w_next, F, WCf, P, cnt, out);
}

// Round 11
// 30.120 us; speedup vs baseline: 4.9498x; 4.9498x over previous
//
#include <hip/hip_runtime.h>
#include <hip/hip_bf16.h>

// B=32, IN_N=8192, POSE=64, M=8, NH=32, S2=256, HID=256, OUT_N=64
//
//  S[b,r][e]   = sum_{p<64} (CP[b, p*128+r] @ WC[p*128+r])[e],  r in [0,128), e=m1*8+m2
//              -> MFMA 16x16x32, 2 r's per wave (diag blocks), p half-split,
//                 DUAL accumulator chains (c and c+4) for load ILP.
//  F[r,e,q]    = sum_{hh<4} E_proj[r>>2, (r&3)*64+e, hh*64+q]
//  pooled[b,q] = (1/64) sum_j S[b,j] * F[j,q]
//     fused pool: each F row read once per block, applied to both b's;
//     cross-wave LDS reduction -> one P slot per (b, block).
//  out[b,o,m1,m2] = sum_k (pooled[b,m1*8+k]+rel[m1*8+k]) * w_next[o,k,m2]

typedef short short8_t __attribute__((ext_vector_type(8)));
typedef float f32x4_t __attribute__((ext_vector_type(4)));
typedef int   int4_t  __attribute__((ext_vector_type(4)));

__device__ __forceinline__ short f2bf(float f) {
    union { float f; unsigned u; } v; v.f = f;
    unsigned r = v.u + 0x7FFFu + ((v.u >> 16) & 1u);   // RNE
    return (short)(r >> 16);
}

// packed f32x2 -> bf16x2 via HW instruction (no builtin on gfx950; m240)
__device__ __forceinline__ int cvt_pk(float x, float y) {
    int r;
    asm("v_cvt_pk_bf16_f32 %0, %1, %2" : "=v"(r) : "v"(x), "v"(y));
    return r;
}

// ---------- Kernel PREP: fused {WCf pack, E-fold} (identical to R6/R9) ----------
__global__ void k_prep(const float* __restrict__ WC, short* __restrict__ WCf,
                       const float* __restrict__ E, float* __restrict__ F) {
    if (blockIdx.x < 256) {
        int t   = blockIdx.x * 256 + threadIdx.x;  // [0, 65536)
        int l   = t & 63;
        int pc  = (t >> 6) & 15;
        int rp  = t >> 10;
        int lhi = l >> 4;
        int j   = l & 15;
        int row = (pc * 4 + lhi) * 128 + rp * 2 + (j >> 3);
        const float* src = WC + ((size_t)row << 6) + (j & 7);
        short8_t o;
        #pragma unroll
        for (int k = 0; k < 8; ++k) o[k] = f2bf(src[k * 8]);
        ((short8_t*)WCf)[t] = o;
    } else {
        int idx = ((blockIdx.x - 256) * 256 + threadIdx.x) * 4;  // [0, 524288)
        int q   = idx & 63;
        int row = idx >> 6;
        int r   = row >> 6;
        int e   = row & 63;
        int nh  = r >> 2;
        int s2  = ((r & 3) << 6) + e;
        const float* base = E + (((size_t)nh * 256 + s2) << 8) + q;
        float4 s0 = *(const float4*)(base);
        float4 s1 = *(const float4*)(base + 64);
        float4 s2v = *(const float4*)(base + 128);
        float4 s3 = *(const float4*)(base + 192);
        float4 o;
        o.x = s0.x + s1.x + s2v.x + s3.x;
        o.y = s0.y + s1.y + s2v.y + s3.y;
        o.z = s0.z + s1.z + s2v.z + s3.z;
        o.w = s0.w + s1.w + s2v.w + s3.w;
        *(float4*)(F + idx) = o;
    }
}

// ---------- Kernel BC: dual-chain MFMA + fused pool + block reduction ----------
// grid (32, 16): gx = rpg*2+half, gy = bq (b0 = bq*2). 512 threads = 8 waves.
// wave w: b = b0 + (w&1), rp = rpg*4 + (w>>1).
__global__ void __launch_bounds__(512, 4)
k_bc(const float* __restrict__ CP, const short* __restrict__ WCf,
     const float* __restrict__ F, float* __restrict__ P) {
    int gx   = blockIdx.x;
    int half = gx & 1;
    int rpg  = gx >> 1;              // [0,16)
    int b0   = blockIdx.y * 2;
    int w = threadIdx.x >> 6;        // [0,8)
    int l = threadIdx.x & 63;
    int b_loc  = w & 1;
    int rp_loc = w >> 1;             // [0,4)
    int rp = rpg * 4 + rp_loc;       // [0,64)
    int r0 = rp * 2;
    int b  = b0 + b_loc;

    int i16   = l & 15;
    int r_sel = i16 >> 3;
    int m1    = i16 & 7;
    int lhi   = l >> 4;              // [0,4)

    __shared__ float Stile[2][512];  // [b_loc][j_loc]
    __shared__ float redp[8][2][64]; // [wave][b_loc][q]

    const float* cp_base = CP + ((size_t)b << 19) + ((size_t)(r0 + r_sel) << 6) + m1 * 8;
    const short8_t* wf   = (const short8_t*)WCf + (size_t)rp * 1024 + (half * 8) * 64 + l;

    // Dual independent accumulator chains: c (chain A) and c+4 (chain B).
    f32x4_t acc0 = {0.f, 0.f, 0.f, 0.f};
    f32x4_t acc1 = {0.f, 0.f, 0.f, 0.f};
    #pragma unroll
    for (int cc = 0; cc < 4; ++cc) {
        int pA = (half * 8 + cc) * 4 + lhi;
        int pB = (half * 8 + cc + 4) * 4 + lhi;
        const float* aA = cp_base + ((size_t)pA << 13);
        const float* aB = cp_base + ((size_t)pB << 13);
        float4 a0 = *(const float4*)(aA);
        float4 a1 = *(const float4*)(aA + 4);
        float4 c0 = *(const float4*)(aB);
        float4 c1 = *(const float4*)(aB + 4);
        short8_t wfA = wf[cc * 64];
        short8_t wfB = wf[(cc + 4) * 64];
        int4_t aiA, aiB;
        aiA[0] = cvt_pk(a0.x, a0.y);
        aiA[1] = cvt_pk(a0.z, a0.w);
        aiA[2] = cvt_pk(a1.x, a1.y);
        aiA[3] = cvt_pk(a1.z, a1.w);
        aiB[0] = cvt_pk(c0.x, c0.y);
        aiB[1] = cvt_pk(c0.z, c0.w);
        aiB[2] = cvt_pk(c1.x, c1.y);
        aiB[3] = cvt_pk(c1.z, c1.w);
        acc0 = __builtin_amdgcn_mfma_f32_16x16x32_bf16(
            __builtin_bit_cast(short8_t, aiA), wfA, acc0, 0, 0, 0);
        acc1 = __builtin_amdgcn_mfma_f32_16x16x32_bf16(
            __builtin_bit_cast(short8_t, aiB), wfB, acc1, 0, 0, 0);
    }
    f32x4_t acc;
    #pragma unroll
    for (int v = 0; v < 4; ++v) acc[v] = acc0[v] + acc1[v];

    // C/D layout (m89-verified): col = lane&15, row = (lane>>4)*4 + reg
    int col = i16;
    #pragma unroll
    for (int v = 0; v < 4; ++v) {
        int row = lhi * 4 + v;
        if (row < 8 && col < 8)
            Stile[b_loc][rp_loc * 128 + row * 8 + col] = acc[v];
        else if (row >= 8 && col >= 8)
            Stile[b_loc][rp_loc * 128 + 64 + (row - 8) * 8 + (col - 8)] = acc[v];
    }
    __syncthreads();

    // Pool phase: wave w covers jl in [w*64, w*64+64); each F row read once,
    // applied to BOTH b's. lane: g = l>>4 (j within quad), ql = l&15 (q = ql*4+c).
    int g  = l >> 4;
    int ql = l & 15;
    const float* Fb = F + (((size_t)(rpg * 512 + w * 64 + g)) << 6) + ql * 4;
    f32x4_t p0 = {0.f, 0.f, 0.f, 0.f};
    f32x4_t p1 = {0.f, 0.f, 0.f, 0.f};
    #pragma unroll 4
    for (int s = 0; s < 16; ++s) {
        int jl = w * 64 + s * 4 + g;
        float4 fv = *(const float4*)(Fb + ((size_t)(s * 4) << 6));
        float s0 = Stile[0][jl];
        float s1 = Stile[1][jl];
        p0[0] += s0 * fv.x; p0[1] += s0 * fv.y; p0[2] += s0 * fv.z; p0[3] += s0 * fv.w;
        p1[0] += s1 * fv.x; p1[1] += s1 * fv.y; p1[2] += s1 * fv.z; p1[3] += s1 * fv.w;
    }
    // reduce over g groups (lanes xor 16, 32); lanes 0-15 hold the wave partial
    #pragma unroll
    for (int c = 0; c < 4; ++c) {
        p0[c] += __shfl_xor(p0[c], 16, 64);
        p0[c] += __shfl_xor(p0[c], 32, 64);
        p1[c] += __shfl_xor(p1[c], 16, 64);
        p1[c] += __shfl_xor(p1[c], 32, 64);
    }
    if (l < 16) {
        *(f32x4_t*)(&redp[w][0][ql * 4]) = p0;
        *(f32x4_t*)(&redp[w][1][ql * 4]) = p1;
    }
    __syncthreads();

    // Cross-wave reduction: threads 0..127 -> (b_loc = t>>6, q = t&63)
    if (threadIdx.x < 128) {
        int bb = threadIdx.x >> 6;
        int q  = threadIdx.x & 63;
        float s = 0.f;
        #pragma unroll
        for (int ww = 0; ww < 8; ++ww) s += redp[ww][bb][q];
        P[((size_t)((b0 + bb) * 32 + gx) << 6) + q] = s;
    }
}

// ---------- Kernel FINAL ----------
// grid (32): b. pooled[b,q] = (1/64)*sum_{sp<32} P[b][sp][q]; epilogue GEMM.
__global__ void k_final(const float* __restrict__ P, const float* __restrict__ rel,
                        const float* __restrict__ WN, float* __restrict__ out) {
    int b  = blockIdx.x;
    int t  = threadIdx.x;
    int q    = t & 63;
    int sgrp = t >> 6;               // [0,4): 8 slots each
    const float* Pb = P + ((size_t)(b * 32) << 6);
    float s = 0.f;
    #pragma unroll
    for (int c = sgrp * 8; c < sgrp * 8 + 8; ++c)
        s += Pb[((size_t)c << 6) + q];
    __shared__ float red[4][64];
    red[sgrp][q] = s;
    __syncthreads();
    __shared__ float pool_s[64];
    if (t < 64) {
        pool_s[t] = (red[0][t] + red[1][t] + red[2][t] + red[3][t]) * (1.0f / 64.0f)
                    + rel[t];
    }
    __syncthreads();
    #pragma unroll
    for (int idx = t; idx < 4096; idx += 256) {
        int o = idx >> 6;
        int e = idx & 63;
        int m1 = e >> 3, m2 = e & 7;
        float a = 0.f;
        #pragma unroll
        for (int k = 0; k < 8; ++k)
            a += pool_s[m1 * 8 + k] * WN[o * 64 + k * 8 + m2];
        out[((size_t)b << 12) + idx] = a;
    }
}

extern "C" void kernel_launch(void* const* d_in, const int* in_sizes, int n_in,
                              void* d_out, int out_size, void* d_ws, size_t ws_size,
                              hipStream_t stream) {
    const float* current_pose = (const float*)d_in[0];  // (32, 8192, 64)
    const float* w_current    = (const float*)d_in[1];  // (1,1,8192,8,8)
    const float* w_next       = (const float*)d_in[2];  // (64,8,8)
    const float* E_proj       = (const float*)d_in[3];  // (32,256,256)
    const float* rel_embedd   = (const float*)d_in[4];  // (1,1,64)
    float* out = (float*)d_out;                         // (32,1,64,64)

    char* ws = (char*)d_ws;
    float* F   = (float*)(ws);                    // 2 MiB
    short* WCf = (short*)(ws + (2u << 20));       // 1 MiB
    float* P   = (float*)(ws + (3u << 20));       // 256 KiB (32 x 32 x 64)

    // PREP: WCf pack (256 blocks) + E fold (512 blocks)
    k_prep<<<dim3(768), dim3(256), 0, stream>>>(w_current, WCf, E_proj, F);
    // BC: dual-chain MFMA + fused pool + block reduction (the 64 MB stream)
    k_bc<<<dim3(32, 16), dim3(512), 0, stream>>>(current_pose, WCf, F, P);
    // FINAL
    k_final<<<dim3(32), dim3(256), 0, stream>>>(P, rel_embedd, w_next, out);
}

// Round 12
// 28.297 us; speedup vs baseline: 5.2687x; 1.0644x over previous
//
#include <hip/hip_runtime.h>
#include <hip/hip_bf16.h>

// B=32, IN_N=8192, POSE=64, M=8, NH=32, S2=256, HID=256, OUT_N=64
//
//  S[b,r][e]   = sum_{p<64} (CP[b, p*128+r] @ WC[p*128+r])[e],  r in [0,128), e=m1*8+m2
//              -> MFMA 16x16x32, 2 r's per wave (diag blocks), p half-split.
//              Stream loop: explicit 2-deep software pipeline (4 chunk-pairs),
//              all 8 WCf fragments pre-loaded to registers.
//  F[r,e,q]    = sum_{hh<4} E_proj[r>>2, (r&3)*64+e, hh*64+q]
//  pooled[b,q] = (1/64) sum_j S[b,j] * F[j,q]
//     fused pool: each F row read once per block, applied to both b's;
//     cross-wave LDS reduction -> one P slot per (b, block).
//  out[b,o,m1,m2] = sum_k (pooled[b,m1*8+k]+rel[m1*8+k]) * w_next[o,k,m2]

typedef short short8_t __attribute__((ext_vector_type(8)));
typedef float f32x4_t __attribute__((ext_vector_type(4)));
typedef int   int4_t  __attribute__((ext_vector_type(4)));

__device__ __forceinline__ short f2bf(float f) {
    union { float f; unsigned u; } v; v.f = f;
    unsigned r = v.u + 0x7FFFu + ((v.u >> 16) & 1u);   // RNE
    return (short)(r >> 16);
}

// packed f32x2 -> bf16x2 via HW instruction (no builtin on gfx950; m240)
__device__ __forceinline__ int cvt_pk(float x, float y) {
    int r;
    asm("v_cvt_pk_bf16_f32 %0, %1, %2" : "=v"(r) : "v"(x), "v"(y));
    return r;
}

// ---------- Kernel PREP: fused {WCf pack, E-fold} (identical to R6/R9/R11) ----------
__global__ void k_prep(const float* __restrict__ WC, short* __restrict__ WCf,
                       const float* __restrict__ E, float* __restrict__ F) {
    if (blockIdx.x < 256) {
        int t   = blockIdx.x * 256 + threadIdx.x;  // [0, 65536)
        int l   = t & 63;
        int pc  = (t >> 6) & 15;
        int rp  = t >> 10;
        int lhi = l >> 4;
        int j   = l & 15;
        int row = (pc * 4 + lhi) * 128 + rp * 2 + (j >> 3);
        const float* src = WC + ((size_t)row << 6) + (j & 7);
        short8_t o;
        #pragma unroll
        for (int k = 0; k < 8; ++k) o[k] = f2bf(src[k * 8]);
        ((short8_t*)WCf)[t] = o;
    } else {
        int idx = ((blockIdx.x - 256) * 256 + threadIdx.x) * 4;  // [0, 524288)
        int q   = idx & 63;
        int row = idx >> 6;
        int r   = row >> 6;
        int e   = row & 63;
        int nh  = r >> 2;
        int s2  = ((r & 3) << 6) + e;
        const float* base = E + (((size_t)nh * 256 + s2) << 8) + q;
        float4 s0 = *(const float4*)(base);
        float4 s1 = *(const float4*)(base + 64);
        float4 s2v = *(const float4*)(base + 128);
        float4 s3 = *(const float4*)(base + 192);
        float4 o;
        o.x = s0.x + s1.x + s2v.x + s3.x;
        o.y = s0.y + s1.y + s2v.y + s3.y;
        o.z = s0.z + s1.z + s2v.z + s3.z;
        o.w = s0.w + s1.w + s2v.w + s3.w;
        *(float4*)(F + idx) = o;
    }
}

// ---------- Kernel BC: pipelined stream + MFMA + fused pool ----------
// grid (32, 16): gx = rpg*2+half, gy = bq (b0 = bq*2). 512 threads = 8 waves.
// wave w: b = b0 + (w&1), rp = rpg*4 + (w>>1).
__global__ void __launch_bounds__(512, 4)
k_bc(const float* __restrict__ CP, const short* __restrict__ WCf,
     const float* __restrict__ F, float* __restrict__ P) {
    int gx   = blockIdx.x;
    int half = gx & 1;
    int rpg  = gx >> 1;              // [0,16)
    int b0   = blockIdx.y * 2;
    int w = threadIdx.x >> 6;        // [0,8)
    int l = threadIdx.x & 63;
    int b_loc  = w & 1;
    int rp_loc = w >> 1;             // [0,4)
    int rp = rpg * 4 + rp_loc;       // [0,64)
    int r0 = rp * 2;
    int b  = b0 + b_loc;

    int i16   = l & 15;
    int r_sel = i16 >> 3;
    int m1    = i16 & 7;
    int lhi   = l >> 4;              // [0,4)

    __shared__ float Stile[2][512];  // [b_loc][j_loc]
    __shared__ float redp[8][2][64]; // [wave][b_loc][q]

    const float* cp_base = CP + ((size_t)b << 19) + ((size_t)(r0 + r_sel) << 6) + m1 * 8;
    const short8_t* wf   = (const short8_t*)WCf + (size_t)rp * 1024 + (half * 8) * 64 + l;

    // Pre-load ALL 8 B-fragments into registers (breaks per-iter L2 latency chain)
    short8_t wr0 = wf[0 * 64], wr1 = wf[1 * 64], wr2 = wf[2 * 64], wr3 = wf[3 * 64];
    short8_t wr4 = wf[4 * 64], wr5 = wf[5 * 64], wr6 = wf[6 * 64], wr7 = wf[7 * 64];

    // chunk c -> row block at p = (half*8+c)*4 + lhi;  addr = cp_base + p*8192 floats
    const float* pbase = cp_base + (((size_t)(half * 8) * 4 + lhi) << 13);
    // pair k covers chunks {2k, 2k+1}: offsets (2k*4)<<13 and (2k*4+... ) in floats
    #define CPA(c) (pbase + ((size_t)((c) * 4) << 13))

    // ---- explicit 2-deep pipeline over 4 pairs ----
    float4 a0A, a1A, b0A, b1A;   // pair 0
    float4 a0B, a1B, b0B, b1B;   // pair 1
    float4 a0C, a1C, b0C, b1C;   // pair 2
    float4 a0D, a1D, b0D, b1D;   // pair 3

    // issue pair 0 and pair 1 loads
    a0A = *(const float4*)(CPA(0));     a1A = *(const float4*)(CPA(0) + 4);
    b0A = *(const float4*)(CPA(1));     b1A = *(const float4*)(CPA(1) + 4);
    a0B = *(const float4*)(CPA(2));     a1B = *(const float4*)(CPA(2) + 4);
    b0B = *(const float4*)(CPA(3));     b1B = *(const float4*)(CPA(3) + 4);

    f32x4_t acc0 = {0.f, 0.f, 0.f, 0.f};
    f32x4_t acc1 = {0.f, 0.f, 0.f, 0.f};

    #define DO_PAIR(x0, x1, y0, y1, wlo, whi)                                  \
    {                                                                          \
        int4_t ai, bi;                                                         \
        ai[0] = cvt_pk(x0.x, x0.y); ai[1] = cvt_pk(x0.z, x0.w);                \
        ai[2] = cvt_pk(x1.x, x1.y); ai[3] = cvt_pk(x1.z, x1.w);                \
        bi[0] = cvt_pk(y0.x, y0.y); bi[1] = cvt_pk(y0.z, y0.w);                \
        bi[2] = cvt_pk(y1.x, y1.y); bi[3] = cvt_pk(y1.z, y1.w);                \
        acc0 = __builtin_amdgcn_mfma_f32_16x16x32_bf16(                        \
            __builtin_bit_cast(short8_t, ai), wlo, acc0, 0, 0, 0);             \
        acc1 = __builtin_amdgcn_mfma_f32_16x16x32_bf16(                        \
            __builtin_bit_cast(short8_t, bi), whi, acc1, 0, 0, 0);             \
    }

    // issue pair 2, compute pair 0
    a0C = *(const float4*)(CPA(4));     a1C = *(const float4*)(CPA(4) + 4);
    b0C = *(const float4*)(CPA(5));     b1C = *(const float4*)(CPA(5) + 4);
    DO_PAIR(a0A, a1A, b0A, b1A, wr0, wr1);
    // issue pair 3, compute pair 1
    a0D = *(const float4*)(CPA(6));     a1D = *(const float4*)(CPA(6) + 4);
    b0D = *(const float4*)(CPA(7));     b1D = *(const float4*)(CPA(7) + 4);
    DO_PAIR(a0B, a1B, b0B, b1B, wr2, wr3);
    // drain
    DO_PAIR(a0C, a1C, b0C, b1C, wr4, wr5);
    DO_PAIR(a0D, a1D, b0D, b1D, wr6, wr7);
    #undef DO_PAIR
    #undef CPA

    f32x4_t acc;
    #pragma unroll
    for (int v = 0; v < 4; ++v) acc[v] = acc0[v] + acc1[v];

    // C/D layout (m89-verified): col = lane&15, row = (lane>>4)*4 + reg
    int col = i16;
    #pragma unroll
    for (int v = 0; v < 4; ++v) {
        int row = lhi * 4 + v;
        if (row < 8 && col < 8)
            Stile[b_loc][rp_loc * 128 + row * 8 + col] = acc[v];
        else if (row >= 8 && col >= 8)
            Stile[b_loc][rp_loc * 128 + 64 + (row - 8) * 8 + (col - 8)] = acc[v];
    }
    __syncthreads();

    // Pool phase: wave w covers jl in [w*64, w*64+64); each F row read once,
    // applied to BOTH b's. lane: g = l>>4 (j within quad), ql = l&15 (q = ql*4+c).
    int g  = l >> 4;
    int ql = l & 15;
    const float* Fb = F + (((size_t)(rpg * 512 + w * 64 + g)) << 6) + ql * 4;
    f32x4_t p0 = {0.f, 0.f, 0.f, 0.f};
    f32x4_t p1 = {0.f, 0.f, 0.f, 0.f};
    #pragma unroll 4
    for (int s = 0; s < 16; ++s) {
        int jl = w * 64 + s * 4 + g;
        float4 fv = *(const float4*)(Fb + ((size_t)(s * 4) << 6));
        float s0 = Stile[0][jl];
        float s1 = Stile[1][jl];
        p0[0] += s0 * fv.x; p0[1] += s0 * fv.y; p0[2] += s0 * fv.z; p0[3] += s0 * fv.w;
        p1[0] += s1 * fv.x; p1[1] += s1 * fv.y; p1[2] += s1 * fv.z; p1[3] += s1 * fv.w;
    }
    #pragma unroll
    for (int c = 0; c < 4; ++c) {
        p0[c] += __shfl_xor(p0[c], 16, 64);
        p0[c] += __shfl_xor(p0[c], 32, 64);
        p1[c] += __shfl_xor(p1[c], 16, 64);
        p1[c] += __shfl_xor(p1[c], 32, 64);
    }
    if (l < 16) {
        *(f32x4_t*)(&redp[w][0][ql * 4]) = p0;
        *(f32x4_t*)(&redp[w][1][ql * 4]) = p1;
    }
    __syncthreads();

    // Cross-wave reduction: threads 0..127 -> (b_loc = t>>6, q = t&63)
    if (threadIdx.x < 128) {
        int bb = threadIdx.x >> 6;
        int q  = threadIdx.x & 63;
        float s = 0.f;
        #pragma unroll
        for (int ww = 0; ww < 8; ++ww) s += redp[ww][bb][q];
        P[((size_t)((b0 + bb) * 32 + gx) << 6) + q] = s;
    }
}

// ---------- Kernel FINAL ----------
// grid (32): b. pooled[b,q] = (1/64)*sum_{sp<32} P[b][sp][q]; epilogue GEMM.
__global__ void k_final(const float* __restrict__ P, const float* __restrict__ rel,
                        const float* __restrict__ WN, float* __restrict__ out) {
    int b  = blockIdx.x;
    int t  = threadIdx.x;
    int q    = t & 63;
    int sgrp = t >> 6;               // [0,4): 8 slots each
    const float* Pb = P + ((size_t)(b * 32) << 6);
    float s = 0.f;
    #pragma unroll
    for (int c = sgrp * 8; c < sgrp * 8 + 8; ++c)
        s += Pb[((size_t)c << 6) + q];
    __shared__ float red[4][64];
    red[sgrp][q] = s;
    __syncthreads();
    __shared__ float pool_s[64];
    if (t < 64) {
        pool_s[t] = (red[0][t] + red[1][t] + red[2][t] + red[3][t]) * (1.0f / 64.0f)
                    + rel[t];
    }
    __syncthreads();
    #pragma unroll
    for (int idx = t; idx < 4096; idx += 256) {
        int o = idx >> 6;
        int e = idx & 63;
        int m1 = e >> 3, m2 = e & 7;
        float a = 0.f;
        #pragma unroll
        for (int k = 0; k < 8; ++k)
            a += pool_s[m1 * 8 + k] * WN[o * 64 + k * 8 + m2];
        out[((size_t)b << 12) + idx] = a;
    }
}

extern "C" void kernel_launch(void* const* d_in, const int* in_sizes, int n_in,
                              void* d_out, int out_size, void* d_ws, size_t ws_size,
                              hipStream_t stream) {
    const float* current_pose = (const float*)d_in[0];  // (32, 8192, 64)
    const float* w_current    = (const float*)d_in[1];  // (1,1,8192,8,8)
    const float* w_next       = (const float*)d_in[2];  // (64,8,8)
    const float* E_proj       = (const float*)d_in[3];  // (32,256,256)
    const float* rel_embedd   = (const float*)d_in[4];  // (1,1,64)
    float* out = (float*)d_out;                         // (32,1,64,64)

    char* ws = (char*)d_ws;
    float* F   = (float*)(ws);                    // 2 MiB
    short* WCf = (short*)(ws + (2u << 20));       // 1 MiB
    float* P   = (float*)(ws + (3u << 20));       // 256 KiB (32 x 32 x 64)

    // PREP: WCf pack (256 blocks) + E fold (512 blocks)
    k_prep<<<dim3(768), dim3(256), 0, stream>>>(w_current, WCf, E_proj, F);
    // BC: explicitly pipelined stream + MFMA + fused pool
    k_bc<<<dim3(32, 16), dim3(512), 0, stream>>>(current_pose, WCf, F, P);
    // FINAL
    k_final<<<dim3(32), dim3(256), 0, stream>>>(P, rel_embedd, w_next, out);
}